// Round 3
// baseline (4477.750 us; speedup 1.0000x reference)
//
#include <hip/hip_runtime.h>
#include <hip/hip_bf16.h>
#include <math.h>
#include <stdint.h>

// GPT-2 forward on MI355X (gfx950).
// GEMMs: split-bf16 (hi/lo) MFMA, fused 3-term k-loop, global_load_lds staging.
// Shapes: B=2, T=1024, E=768, H=12, D=64, L=6, R=4, V=50257.

#define T_SEQ 1024
#define E_DIM 768
#define NHEAD 12
#define HDIM 64
#define NLAYER 6
#define VOCAB 50257
#define VPAD 50304          // vocab padded to multiple of 128
#define BT 2048             // B*T rows

typedef __attribute__((ext_vector_type(8))) short bf16x8;
typedef __attribute__((ext_vector_type(4))) float f32x4;

static __device__ __forceinline__ ushort f2bf(float x) {   // fp32 -> bf16 RNE
    uint u = __float_as_uint(x);
    uint r = (u + 0x7fffu + ((u >> 16) & 1u)) >> 16;
    return (ushort)r;
}
static __device__ __forceinline__ float bf2f(ushort u) {
    return __uint_as_float(((uint)u) << 16);
}

// async global -> LDS, 16B per lane, dest = uniform base + lane*16
static __device__ __forceinline__ void gld16(const ushort* g, ushort* l) {
    __builtin_amdgcn_global_load_lds(
        (const __attribute__((address_space(1))) void*)g,
        (__attribute__((address_space(3))) void*)l, 16, 0, 0);
}

// ---------------------------------------------------------------------------
// Embedding
// ---------------------------------------------------------------------------
__global__ __launch_bounds__(192) void embed_k(const int* __restrict__ x,
                                               const float* __restrict__ tok,
                                               const float* __restrict__ pos,
                                               float* __restrict__ h) {
    int bt = blockIdx.x;
    int t = bt & (T_SEQ - 1);
    int id = x[bt];
    float4 a = ((const float4*)(tok + (size_t)id * E_DIM))[threadIdx.x];
    float4 b = ((const float4*)(pos + (size_t)t * E_DIM))[threadIdx.x];
    float4 r; r.x = a.x + b.x; r.y = a.y + b.y; r.z = a.z + b.z; r.w = a.w + b.w;
    ((float4*)(h + (size_t)bt * E_DIM))[threadIdx.x] = r;
}

// ---------------------------------------------------------------------------
// LayerNorm -> bf16 hi/lo outputs (feeds GEMM A). One block per row.
// ---------------------------------------------------------------------------
__global__ __launch_bounds__(256) void ln_k(const float* __restrict__ in,
                                            const float* __restrict__ w,
                                            const float* __restrict__ b,
                                            ushort* __restrict__ oh,
                                            ushort* __restrict__ ol) {
    int rid = blockIdx.x;
    int tid = threadIdx.x;
    const float* rp = in + (size_t)rid * E_DIM;
    float x0 = rp[tid], x1 = rp[tid + 256], x2 = rp[tid + 512];
    float s = x0 + x1 + x2;
    float q = x0 * x0 + x1 * x1 + x2 * x2;
    #pragma unroll
    for (int off = 32; off >= 1; off >>= 1) {
        s += __shfl_down(s, off);
        q += __shfl_down(q, off);
    }
    __shared__ float ss[4], qq[4];
    int lane = tid & 63, wid = tid >> 6;
    if (lane == 0) { ss[wid] = s; qq[wid] = q; }
    __syncthreads();
    float S = ss[0] + ss[1] + ss[2] + ss[3];
    float Q = qq[0] + qq[1] + qq[2] + qq[3];
    float mean = S * (1.0f / E_DIM);
    float var = Q * (1.0f / E_DIM) - mean * mean;
    float inv = rsqrtf(var + 1e-5f);
    size_t ob = (size_t)rid * E_DIM;
    #pragma unroll
    for (int j = 0; j < 3; j++) {
        int c = tid + j * 256;
        float xv = (j == 0) ? x0 : (j == 1) ? x1 : x2;
        float y = (xv - mean) * inv * w[c] + b[c];
        ushort hh = f2bf(y);
        oh[ob + c] = hh;
        ol[ob + c] = f2bf(y - bf2f(hh));
    }
}

// ---------------------------------------------------------------------------
// Weight transpose + bf16 hi/lo split: W[K,N] fp32 -> Thi/Tlo[Npad,K] bf16.
// Zero-fills n in [N, Npad).
// ---------------------------------------------------------------------------
__global__ __launch_bounds__(256) void tconv_k(const float* __restrict__ W,
                                               ushort* __restrict__ Thi,
                                               ushort* __restrict__ Tlo,
                                               int K, int N, int Npad) {
    int k0 = blockIdx.x * 32, n0 = blockIdx.y * 32;
    __shared__ float tile[32][33];
    int t = threadIdx.x;
    int kr = t >> 3, nc = (t & 7) << 2;
    const float* wp = W + (size_t)(k0 + kr) * N + n0 + nc;
    #pragma unroll
    for (int j = 0; j < 4; j++)
        tile[kr][nc + j] = (n0 + nc + j < N) ? wp[j] : 0.f;
    __syncthreads();
    int nr = t >> 3, kc = (t & 7) << 2;
    ushort hv[4], lv[4];
    #pragma unroll
    for (int j = 0; j < 4; j++) {
        float x = tile[kc + j][nr];
        hv[j] = f2bf(x);
        lv[j] = f2bf(x - bf2f(hv[j]));
    }
    size_t ob = (size_t)(n0 + nr) * K + k0 + kc;
    uint2 ph, pl;
    ph.x = (uint)hv[0] | ((uint)hv[1] << 16); ph.y = (uint)hv[2] | ((uint)hv[3] << 16);
    pl.x = (uint)lv[0] | ((uint)lv[1] << 16); pl.y = (uint)lv[2] | ((uint)lv[3] << 16);
    *(uint2*)(Thi + ob) = ph;
    *(uint2*)(Tlo + ob) = pl;
}

// ---------------------------------------------------------------------------
// Fused split-bf16 MFMA GEMM:
//   C = Ahi@Bhi^T + Ahi@Blo^T + Alo@Bhi^T   (A [M][K] bf16, B [Npad][K] bf16)
// Block 128x128, 256 thr (4 waves 2x2, 64x64/wave), BK=32, 16x16x32 MFMA.
// Staging via global_load_lds (linear LDS dest); granule-XOR swizzle
// (chunk ^= (row>>1)&3) applied to SOURCE addr and READ addr (involution).
// EPI: 0 = bias->C fp32, 1 = bias+GELU(exact)->Chi/Clo bf16, 2 = bias+res->C.
// ---------------------------------------------------------------------------
template <int EPI>
__global__ __launch_bounds__(256) void gemmf_k(const ushort* __restrict__ Ahi,
                                               const ushort* __restrict__ Alo,
                                               const ushort* __restrict__ Bhi,
                                               const ushort* __restrict__ Blo,
                                               const float* __restrict__ bias,
                                               const float* __restrict__ res,
                                               float* __restrict__ C,
                                               ushort* __restrict__ Chi,
                                               ushort* __restrict__ Clo,
                                               int M, int N, int K) {
    __shared__ __align__(16) ushort lds[4 * 128 * 32];
    ushort* Ash = lds;
    ushort* Asl = lds + 4096;
    ushort* Bsh = lds + 8192;
    ushort* Bsl = lds + 12288;
    const int tid = threadIdx.x;
    const int lane = tid & 63;
    const int wave = tid >> 6;
    const int wm64 = (wave >> 1) * 64;
    const int wn64 = (wave & 1) * 64;
    const int lrow = lane & 15;
    const int lkc = lane >> 4;
    const int n0 = blockIdx.x * 128;
    const int m0 = blockIdx.y * 128;

    f32x4 acc[4][4];
    #pragma unroll
    for (int i = 0; i < 4; i++)
        #pragma unroll
        for (int j = 0; j < 4; j++)
            acc[i][j] = (f32x4){0.f, 0.f, 0.f, 0.f};

    // staging: wave w covers 16-row strips {w, w+4} of each 128-row tile.
    const int r0s = wave * 16 + (lane >> 2);       // rows 0..63
    const int r1s = r0s + 64;                      // rows 64..127
    const int c0s = ((lane & 3) ^ ((r0s >> 1) & 3)) << 3;  // swizzled src chunk
    const int c1s = ((lane & 3) ^ ((r1s >> 1) & 3)) << 3;
    const ushort* pAh0 = Ahi + (size_t)(m0 + r0s) * K + c0s;
    const ushort* pAh1 = Ahi + (size_t)(m0 + r1s) * K + c1s;
    const ushort* pAl0 = Alo + (size_t)(m0 + r0s) * K + c0s;
    const ushort* pAl1 = Alo + (size_t)(m0 + r1s) * K + c1s;
    const ushort* pBh0 = Bhi + (size_t)(n0 + r0s) * K + c0s;
    const ushort* pBh1 = Bhi + (size_t)(n0 + r1s) * K + c1s;
    const ushort* pBl0 = Blo + (size_t)(n0 + r0s) * K + c0s;
    const ushort* pBl1 = Blo + (size_t)(n0 + r1s) * K + c1s;
    ushort* dst0 = lds + (size_t)wave * 512;         // strip w   (within tile 0)
    ushort* dst1 = lds + (size_t)(wave + 4) * 512;   // strip w+4

    for (int k0 = 0; k0 < K; k0 += 32) {
        __syncthreads();   // all waves done reading previous tiles
        gld16(pAh0 + k0, dst0);
        gld16(pAh1 + k0, dst1);
        gld16(pAl0 + k0, dst0 + 4096);
        gld16(pAl1 + k0, dst1 + 4096);
        gld16(pBh0 + k0, dst0 + 8192);
        gld16(pBh1 + k0, dst1 + 8192);
        gld16(pBl0 + k0, dst0 + 12288);
        gld16(pBl1 + k0, dst1 + 12288);
        __syncthreads();   // vmcnt drained before barrier -> tiles visible

        bf16x8 ah[4], al[4], bh[4], bl[4];
        #pragma unroll
        for (int f = 0; f < 4; f++) {
            int arow = wm64 + (f << 4) + lrow;
            int aoff = (arow << 5) + ((lkc ^ ((arow >> 1) & 3)) << 3);
            ah[f] = *(const bf16x8*)&Ash[aoff];
            al[f] = *(const bf16x8*)&Asl[aoff];
            int brow = wn64 + (f << 4) + lrow;
            int boff = (brow << 5) + ((lkc ^ ((brow >> 1) & 3)) << 3);
            bh[f] = *(const bf16x8*)&Bsh[boff];
            bl[f] = *(const bf16x8*)&Bsl[boff];
        }
        #pragma unroll
        for (int mf = 0; mf < 4; mf++)
            #pragma unroll
            for (int nf = 0; nf < 4; nf++) {
                acc[mf][nf] = __builtin_amdgcn_mfma_f32_16x16x32_bf16(
                    ah[mf], bh[nf], acc[mf][nf], 0, 0, 0);
                acc[mf][nf] = __builtin_amdgcn_mfma_f32_16x16x32_bf16(
                    ah[mf], bl[nf], acc[mf][nf], 0, 0, 0);
                acc[mf][nf] = __builtin_amdgcn_mfma_f32_16x16x32_bf16(
                    al[mf], bh[nf], acc[mf][nf], 0, 0, 0);
            }
    }

    // epilogue: C/D layout col=lane&15, row=(lane>>4)*4+reg  [m89-verified]
    const int colb = n0 + wn64 + (lane & 15);
    const int rowb = m0 + wm64 + ((lane >> 4) << 2);
    #pragma unroll
    for (int nf = 0; nf < 4; nf++) {
        int col = colb + nf * 16;
        if (col >= N) continue;
        float bv = bias ? bias[col] : 0.f;
        #pragma unroll
        for (int mf = 0; mf < 4; mf++) {
            f32x4 v = acc[mf][nf];
            #pragma unroll
            for (int q = 0; q < 4; q++) {
                int row = rowb + mf * 16 + q;
                size_t idx = (size_t)row * N + col;
                float x = v[q] + bv;
                if (EPI == 1) {
                    x = 0.5f * x * (1.0f + erff(x * 0.70710678118654752f));
                    ushort hh = f2bf(x);
                    Chi[idx] = hh;
                    Clo[idx] = f2bf(x - bf2f(hh));
                } else if (EPI == 2) {
                    x += res[idx];
                    C[idx] = x;
                } else {
                    C[idx] = x;
                }
            }
        }
    }
}

// ---------------------------------------------------------------------------
// Flash-style causal attention (fp32 compute) -> bf16 hi/lo output.
// One block per (qtile=64, head, batch). qkv: [B*T, 3*E] fp32.
// ---------------------------------------------------------------------------
__global__ __launch_bounds__(256) void attn_k(const float* __restrict__ qkv,
                                              ushort* __restrict__ oh,
                                              ushort* __restrict__ ol) {
    const int qt = blockIdx.x;
    const int hh = blockIdx.y;
    const int bb = blockIdx.z;
    const int tid = threadIdx.x;
    __shared__ __align__(16) float Qs[64][68];
    __shared__ __align__(16) float Ks[64][68];
    __shared__ __align__(16) float Vs[64][68];
    __shared__ __align__(16) float Ssm[64][68];
    __shared__ float m_s[64], l_s[64], f_s[64];

    const int q0 = qt * 64;
    const size_t base = (size_t)bb * T_SEQ * (3 * E_DIM);
    const int hoff = hh * HDIM;

    #pragma unroll
    for (int j = 0; j < 4; j++) {
        int s = tid + j * 256;
        int rr = s >> 4, c4 = (s & 15) << 2;
        *(float4*)&Qs[rr][c4] =
            *(const float4*)(qkv + base + (size_t)(q0 + rr) * (3 * E_DIM) + hoff + c4);
    }
    if (tid < 64) { m_s[tid] = -1e30f; l_s[tid] = 0.f; }

    float acc[4][4] = {};
    const int r0 = (tid >> 4) << 2, c0 = (tid & 15) << 2;
    const int rs = tid >> 2, cq = (tid & 3) << 4;

    for (int kt = 0; kt <= qt; ++kt) {
        int k0 = kt * 64;
        __syncthreads();
        #pragma unroll
        for (int j = 0; j < 4; j++) {
            int s = tid + j * 256;
            int rr = s >> 4, c4 = (s & 15) << 2;
            const float* kp = qkv + base + (size_t)(k0 + rr) * (3 * E_DIM) + hoff;
            *(float4*)&Ks[rr][c4] = *(const float4*)(kp + E_DIM + c4);
            *(float4*)&Vs[rr][c4] = *(const float4*)(kp + 2 * E_DIM + c4);
        }
        __syncthreads();

        float sacc[4][4] = {};
        #pragma unroll
        for (int d0 = 0; d0 < 64; d0 += 4) {
            float qf[4][4], kf[4][4];
            #pragma unroll
            for (int i = 0; i < 4; i++) {
                float4 v = *(const float4*)&Qs[r0 + i][d0];
                qf[i][0] = v.x; qf[i][1] = v.y; qf[i][2] = v.z; qf[i][3] = v.w;
            }
            #pragma unroll
            for (int j = 0; j < 4; j++) {
                float4 v = *(const float4*)&Ks[c0 + j][d0];
                kf[j][0] = v.x; kf[j][1] = v.y; kf[j][2] = v.z; kf[j][3] = v.w;
            }
            #pragma unroll
            for (int i = 0; i < 4; i++)
                #pragma unroll
                for (int j = 0; j < 4; j++)
                    #pragma unroll
                    for (int d = 0; d < 4; d++)
                        sacc[i][j] = fmaf(qf[i][d], kf[j][d], sacc[i][j]);
        }
        bool diag = (kt == qt);
        #pragma unroll
        for (int i = 0; i < 4; i++) {
            float4 w;
            float vv[4];
            #pragma unroll
            for (int j = 0; j < 4; j++) {
                float v = sacc[i][j] * 0.125f;
                if (diag && (c0 + j) > (r0 + i)) v = -1e9f;
                vv[j] = v;
            }
            w.x = vv[0]; w.y = vv[1]; w.z = vv[2]; w.w = vv[3];
            *(float4*)&Ssm[r0 + i][c0] = w;
        }
        __syncthreads();

        float mx = -1e30f;
        #pragma unroll
        for (int c = 0; c < 16; c++) mx = fmaxf(mx, Ssm[rs][cq + c]);
        mx = fmaxf(mx, __shfl_xor(mx, 1));
        mx = fmaxf(mx, __shfl_xor(mx, 2));
        float m_old = m_s[rs];
        float m_new = fmaxf(m_old, mx);
        float ps = 0.f;
        #pragma unroll
        for (int c = 0; c < 16; c++) {
            float p = expf(Ssm[rs][cq + c] - m_new);
            Ssm[rs][cq + c] = p;
            ps += p;
        }
        ps += __shfl_xor(ps, 1);
        ps += __shfl_xor(ps, 2);
        if ((tid & 3) == 0) {
            float f = expf(m_old - m_new);
            l_s[rs] = l_s[rs] * f + ps;
            m_s[rs] = m_new;
            f_s[rs] = f;
        }
        __syncthreads();

        #pragma unroll
        for (int i = 0; i < 4; i++) {
            float f = f_s[r0 + i];
            #pragma unroll
            for (int j = 0; j < 4; j++) acc[i][j] *= f;
        }
        #pragma unroll 8
        for (int k = 0; k < 64; k++) {
            float4 vv = *(const float4*)&Vs[k][c0];
            float vf[4] = {vv.x, vv.y, vv.z, vv.w};
            float pv[4];
            #pragma unroll
            for (int i = 0; i < 4; i++) pv[i] = Ssm[r0 + i][k];
            #pragma unroll
            for (int i = 0; i < 4; i++)
                #pragma unroll
                for (int j = 0; j < 4; j++)
                    acc[i][j] = fmaf(pv[i], vf[j], acc[i][j]);
        }
    }

    #pragma unroll
    for (int i = 0; i < 4; i++) {
        float inv = 1.0f / l_s[r0 + i];
        size_t idx = (size_t)(bb * T_SEQ + q0 + r0 + i) * E_DIM + hoff + c0;
        ushort hv[4], lv[4];
        #pragma unroll
        for (int j = 0; j < 4; j++) {
            float v = acc[i][j] * inv;
            hv[j] = f2bf(v);
            lv[j] = f2bf(v - bf2f(hv[j]));
        }
        uint2 ph, pl;
        ph.x = (uint)hv[0] | ((uint)hv[1] << 16); ph.y = (uint)hv[2] | ((uint)hv[3] << 16);
        pl.x = (uint)lv[0] | ((uint)lv[1] << 16); pl.y = (uint)lv[2] | ((uint)lv[3] << 16);
        *(uint2*)(oh + idx) = ph;
        *(uint2*)(ol + idx) = pl;
    }
}

// ---------------------------------------------------------------------------
// Launch
// ---------------------------------------------------------------------------
static inline char* al256(char* p) {
    return (char*)(((uintptr_t)p + 255) & ~(uintptr_t)255);
}

extern "C" void kernel_launch(void* const* d_in, const int* in_sizes, int n_in,
                              void* d_out, int out_size, void* d_ws, size_t ws_size,
                              hipStream_t stream) {
    const int* x        = (const int*)d_in[0];
    const float* tok    = (const float*)d_in[1];
    const float* pos    = (const float*)d_in[2];
    const float* ln1_w  = (const float*)d_in[3];
    const float* ln1_b  = (const float*)d_in[4];
    const float* qkv_w  = (const float*)d_in[5];
    const float* qkv_b  = (const float*)d_in[6];
    const float* out_w  = (const float*)d_in[7];
    const float* out_b  = (const float*)d_in[8];
    const float* ln2_w  = (const float*)d_in[9];
    const float* ln2_b  = (const float*)d_in[10];
    const float* mlp_w1 = (const float*)d_in[11];
    const float* mlp_b1 = (const float*)d_in[12];
    const float* mlp_w2 = (const float*)d_in[13];
    const float* mlp_b2 = (const float*)d_in[14];
    const float* lnf_w  = (const float*)d_in[15];
    const float* lnf_b  = (const float*)d_in[16];
    const float* head_w = (const float*)d_in[17];
    float* out = (float*)d_out;

    // ---- workspace carve (total ~246 MB)
    char* p = (char*)d_ws;
    float* h    = (float*)p;  p = al256(p + (size_t)BT * E_DIM * 4);
    float* qkvb = (float*)p;  p = al256(p + (size_t)BT * 3 * E_DIM * 4);
    ushort* hnh = (ushort*)p; p = al256(p + (size_t)BT * E_DIM * 2);
    ushort* hnl = (ushort*)p; p = al256(p + (size_t)BT * E_DIM * 2);
    ushort* obh = (ushort*)p; p = al256(p + (size_t)BT * E_DIM * 2);
    ushort* obl = (ushort*)p; p = al256(p + (size_t)BT * E_DIM * 2);
    ushort* m1h = (ushort*)p; p = al256(p + (size_t)BT * 4 * E_DIM * 2);
    ushort* m1l = (ushort*)p; p = al256(p + (size_t)BT * 4 * E_DIM * 2);
    ushort* qTh = (ushort*)p; p = al256(p + (size_t)3 * E_DIM * E_DIM * 2);
    ushort* qTl = (ushort*)p; p = al256(p + (size_t)3 * E_DIM * E_DIM * 2);
    ushort* oTh = (ushort*)p; p = al256(p + (size_t)E_DIM * E_DIM * 2);
    ushort* oTl = (ushort*)p; p = al256(p + (size_t)E_DIM * E_DIM * 2);
    ushort* w1h = (ushort*)p; p = al256(p + (size_t)4 * E_DIM * E_DIM * 2);
    ushort* w1l = (ushort*)p; p = al256(p + (size_t)4 * E_DIM * E_DIM * 2);
    ushort* w2h = (ushort*)p; p = al256(p + (size_t)4 * E_DIM * E_DIM * 2);
    ushort* w2l = (ushort*)p; p = al256(p + (size_t)4 * E_DIM * E_DIM * 2);
    ushort* hTh = (ushort*)p; p = al256(p + (size_t)VPAD * E_DIM * 2);
    ushort* hTl = (ushort*)p; p = al256(p + (size_t)VPAD * E_DIM * 2);

    embed_k<<<BT, 192, 0, stream>>>(x, tok, pos, h);

    for (int l = 0; l < NLAYER; ++l) {
        // per-layer weight transpose + split (buffers reused across layers)
        tconv_k<<<dim3(E_DIM / 32, 3 * E_DIM / 32), 256, 0, stream>>>(
            qkv_w + (size_t)l * E_DIM * 3 * E_DIM, qTh, qTl,
            E_DIM, 3 * E_DIM, 3 * E_DIM);
        tconv_k<<<dim3(E_DIM / 32, E_DIM / 32), 256, 0, stream>>>(
            out_w + (size_t)l * E_DIM * E_DIM, oTh, oTl, E_DIM, E_DIM, E_DIM);
        tconv_k<<<dim3(E_DIM / 32, 4 * E_DIM / 32), 256, 0, stream>>>(
            mlp_w1 + (size_t)l * E_DIM * 4 * E_DIM, w1h, w1l,
            E_DIM, 4 * E_DIM, 4 * E_DIM);
        tconv_k<<<dim3(4 * E_DIM / 32, E_DIM / 32), 256, 0, stream>>>(
            mlp_w2 + (size_t)l * 4 * E_DIM * E_DIM, w2h, w2l,
            4 * E_DIM, E_DIM, E_DIM);

        ln_k<<<BT, 256, 0, stream>>>(h, ln1_w + l * E_DIM, ln1_b + l * E_DIM,
                                     hnh, hnl);
        gemmf_k<0><<<dim3(3 * E_DIM / 128, BT / 128), 256, 0, stream>>>(
            hnh, hnl, qTh, qTl, qkv_b + (size_t)l * 3 * E_DIM, nullptr,
            qkvb, nullptr, nullptr, BT, 3 * E_DIM, E_DIM);
        attn_k<<<dim3(T_SEQ / 64, NHEAD, 2), 256, 0, stream>>>(qkvb, obh, obl);
        gemmf_k<2><<<dim3(E_DIM / 128, BT / 128), 256, 0, stream>>>(
            obh, obl, oTh, oTl, out_b + (size_t)l * E_DIM, h,
            h, nullptr, nullptr, BT, E_DIM, E_DIM);
        ln_k<<<BT, 256, 0, stream>>>(h, ln2_w + l * E_DIM, ln2_b + l * E_DIM,
                                     hnh, hnl);
        gemmf_k<1><<<dim3(4 * E_DIM / 128, BT / 128), 256, 0, stream>>>(
            hnh, hnl, w1h, w1l, mlp_b1 + (size_t)l * 4 * E_DIM, nullptr,
            nullptr, m1h, m1l, BT, 4 * E_DIM, E_DIM);
        gemmf_k<2><<<dim3(E_DIM / 128, BT / 128), 256, 0, stream>>>(
            m1h, m1l, w2h, w2l, mlp_b2 + (size_t)l * E_DIM, h,
            h, nullptr, nullptr, BT, E_DIM, 4 * E_DIM);
    }

    tconv_k<<<dim3(E_DIM / 32, VPAD / 32), 256, 0, stream>>>(
        head_w, hTh, hTl, E_DIM, VOCAB, VPAD);
    ln_k<<<BT, 256, 0, stream>>>(h, lnf_w, lnf_b, hnh, hnl);
    gemmf_k<0><<<dim3(VPAD / 128, BT / 128), 256, 0, stream>>>(
        hnh, hnl, hTh, hTl, nullptr, nullptr,
        out, nullptr, nullptr, BT, VOCAB, E_DIM);
}

// Round 5
// 3996.717 us; speedup vs baseline: 1.1204x; 1.1204x over previous
//
#include <hip/hip_runtime.h>
#include <hip/hip_bf16.h>
#include <math.h>
#include <stdint.h>

// GPT-2 forward on MI355X (gfx950).
// GEMMs: split-bf16 (hi/lo) MFMA, fused 3-term k-loop, global_load_lds staging,
// XCD-aware block swizzle, split-K for low-fill GEMMs. Vectorized fp32 attn.
// Shapes: B=2, T=1024, E=768, H=12, D=64, L=6, R=4, V=50257.

#define T_SEQ 1024
#define E_DIM 768
#define NHEAD 12
#define HDIM 64
#define NLAYER 6
#define VOCAB 50257
#define VPAD 50304          // vocab padded to multiple of 128
#define BT 2048             // B*T rows

typedef __attribute__((ext_vector_type(8))) short bf16x8;
typedef __attribute__((ext_vector_type(4))) float f32x4;

static __device__ __forceinline__ ushort f2bf(float x) {   // fp32 -> bf16 RNE
    uint u = __float_as_uint(x);
    uint r = (u + 0x7fffu + ((u >> 16) & 1u)) >> 16;
    return (ushort)r;
}
static __device__ __forceinline__ float bf2f(ushort u) {
    return __uint_as_float(((uint)u) << 16);
}

// async global -> LDS, 16B per lane, dest = uniform base + lane*16
static __device__ __forceinline__ void gld16(const ushort* g, ushort* l) {
    __builtin_amdgcn_global_load_lds(
        (const __attribute__((address_space(1))) void*)g,
        (__attribute__((address_space(3))) void*)l, 16, 0, 0);
}

// ---------------------------------------------------------------------------
// Embedding
// ---------------------------------------------------------------------------
__global__ __launch_bounds__(192) void embed_k(const int* __restrict__ x,
                                               const float* __restrict__ tok,
                                               const float* __restrict__ pos,
                                               float* __restrict__ h) {
    int bt = blockIdx.x;
    int t = bt & (T_SEQ - 1);
    int id = x[bt];
    float4 a = ((const float4*)(tok + (size_t)id * E_DIM))[threadIdx.x];
    float4 b = ((const float4*)(pos + (size_t)t * E_DIM))[threadIdx.x];
    float4 r; r.x = a.x + b.x; r.y = a.y + b.y; r.z = a.z + b.z; r.w = a.w + b.w;
    ((float4*)(h + (size_t)bt * E_DIM))[threadIdx.x] = r;
}

// ---------------------------------------------------------------------------
// LayerNorm -> bf16 hi/lo outputs (feeds GEMM A). One block per row.
// ---------------------------------------------------------------------------
__global__ __launch_bounds__(256) void ln_k(const float* __restrict__ in,
                                            const float* __restrict__ w,
                                            const float* __restrict__ b,
                                            ushort* __restrict__ oh,
                                            ushort* __restrict__ ol) {
    int rid = blockIdx.x;
    int tid = threadIdx.x;
    const float* rp = in + (size_t)rid * E_DIM;
    float x0 = rp[tid], x1 = rp[tid + 256], x2 = rp[tid + 512];
    float s = x0 + x1 + x2;
    float q = x0 * x0 + x1 * x1 + x2 * x2;
    #pragma unroll
    for (int off = 32; off >= 1; off >>= 1) {
        s += __shfl_down(s, off);
        q += __shfl_down(q, off);
    }
    __shared__ float ss[4], qq[4];
    int lane = tid & 63, wid = tid >> 6;
    if (lane == 0) { ss[wid] = s; qq[wid] = q; }
    __syncthreads();
    float S = ss[0] + ss[1] + ss[2] + ss[3];
    float Q = qq[0] + qq[1] + qq[2] + qq[3];
    float mean = S * (1.0f / E_DIM);
    float var = Q * (1.0f / E_DIM) - mean * mean;
    float inv = rsqrtf(var + 1e-5f);
    size_t ob = (size_t)rid * E_DIM;
    #pragma unroll
    for (int j = 0; j < 3; j++) {
        int c = tid + j * 256;
        float xv = (j == 0) ? x0 : (j == 1) ? x1 : x2;
        float y = (xv - mean) * inv * w[c] + b[c];
        ushort hh = f2bf(y);
        oh[ob + c] = hh;
        ol[ob + c] = f2bf(y - bf2f(hh));
    }
}

// ---------------------------------------------------------------------------
// Weight transpose + bf16 hi/lo split: W[K,N] fp32 -> Thi/Tlo[Npad,K] bf16.
// Zero-fills n in [N, Npad). blockIdx.z = layer offset.
// ---------------------------------------------------------------------------
__global__ __launch_bounds__(256) void tconv_k(const float* __restrict__ W,
                                               ushort* __restrict__ Thi,
                                               ushort* __restrict__ Tlo,
                                               int K, int N, int Npad) {
    int l = blockIdx.z;
    W   += (size_t)l * K * N;
    Thi += (size_t)l * Npad * K;
    Tlo += (size_t)l * Npad * K;
    int k0 = blockIdx.x * 32, n0 = blockIdx.y * 32;
    __shared__ float tile[32][33];
    int t = threadIdx.x;
    int kr = t >> 3, nc = (t & 7) << 2;
    const float* wp = W + (size_t)(k0 + kr) * N + n0 + nc;
    #pragma unroll
    for (int j = 0; j < 4; j++)
        tile[kr][nc + j] = (n0 + nc + j < N) ? wp[j] : 0.f;
    __syncthreads();
    int nr = t >> 3, kc = (t & 7) << 2;
    ushort hv[4], lv[4];
    #pragma unroll
    for (int j = 0; j < 4; j++) {
        float x = tile[kc + j][nr];
        hv[j] = f2bf(x);
        lv[j] = f2bf(x - bf2f(hv[j]));
    }
    size_t ob = (size_t)(n0 + nr) * K + k0 + kc;
    uint2 ph, pl;
    ph.x = (uint)hv[0] | ((uint)hv[1] << 16); ph.y = (uint)hv[2] | ((uint)hv[3] << 16);
    pl.x = (uint)lv[0] | ((uint)lv[1] << 16); pl.y = (uint)lv[2] | ((uint)lv[3] << 16);
    *(uint2*)(Thi + ob) = ph;
    *(uint2*)(Tlo + ob) = pl;
}

// ---------------------------------------------------------------------------
// Fused split-bf16 MFMA GEMM:
//   C = Ahi@Bhi^T + Ahi@Blo^T + Alo@Bhi^T   (A [M][K] bf16, B [Npad][K] bf16)
// Block 128x128, 256 thr (4 waves 2x2, 64x64/wave), BK=32, 16x16x32 MFMA.
// global_load_lds staging, granule-XOR swizzle (src+read, involution).
// XCD-aware swizzle: same-XCD-consecutive blocks share a B (N) panel.
// EPI: 0 = bias->C fp32, 1 = bias+GELU(exact)->Chi/Clo bf16, 2 = bias+res->C,
//      3 = split-K partial: K-slice [kz*K/gz, ...), raw acc -> C + kz*M*N.
// ---------------------------------------------------------------------------
template <int EPI>
__global__ __launch_bounds__(256) void gemmf_k(const ushort* __restrict__ Ahi,
                                               const ushort* __restrict__ Alo,
                                               const ushort* __restrict__ Bhi,
                                               const ushort* __restrict__ Blo,
                                               const float* __restrict__ bias,
                                               const float* __restrict__ res,
                                               float* __restrict__ C,
                                               ushort* __restrict__ Chi,
                                               ushort* __restrict__ Clo,
                                               int M, int N, int K) {
    __shared__ __align__(16) ushort lds[4 * 128 * 32];
    ushort* Ash = lds;
    ushort* Asl = lds + 4096;
    ushort* Bsh = lds + 8192;
    ushort* Bsl = lds + 12288;
    const int tid = threadIdx.x;
    const int lane = tid & 63;
    const int wave = tid >> 6;
    const int wm64 = (wave >> 1) * 64;
    const int wn64 = (wave & 1) * 64;
    const int lrow = lane & 15;
    const int lkc = lane >> 4;

    // XCD-aware block swizzle (bijective; plane sizes here are all %8==0).
    int gx = gridDim.x, gy = gridDim.y;
    int nwg = gx * gy;
    int lin = blockIdx.y * gx + blockIdx.x;
    int bx, by;
    if ((nwg & 7) == 0) {
        int chunk = nwg >> 3;
        int logical = (lin & 7) * chunk + (lin >> 3);
        bx = logical / gy;          // consecutive logicals share bx (B panel)
        by = logical % gy;
    } else { bx = blockIdx.x; by = blockIdx.y; }
    const int n0 = bx * 128;
    const int m0 = by * 128;

    f32x4 acc[4][4];
    #pragma unroll
    for (int i = 0; i < 4; i++)
        #pragma unroll
        for (int j = 0; j < 4; j++)
            acc[i][j] = (f32x4){0.f, 0.f, 0.f, 0.f};

    // staging: wave w covers 16-row strips {w, w+4} of each 128-row tile.
    const int r0s = wave * 16 + (lane >> 2);       // rows 0..63
    const int r1s = r0s + 64;                      // rows 64..127
    const int c0s = ((lane & 3) ^ ((r0s >> 1) & 3)) << 3;  // swizzled src chunk
    const int c1s = ((lane & 3) ^ ((r1s >> 1) & 3)) << 3;
    const ushort* pAh0 = Ahi + (size_t)(m0 + r0s) * K + c0s;
    const ushort* pAh1 = Ahi + (size_t)(m0 + r1s) * K + c1s;
    const ushort* pAl0 = Alo + (size_t)(m0 + r0s) * K + c0s;
    const ushort* pAl1 = Alo + (size_t)(m0 + r1s) * K + c1s;
    const ushort* pBh0 = Bhi + (size_t)(n0 + r0s) * K + c0s;
    const ushort* pBh1 = Bhi + (size_t)(n0 + r1s) * K + c1s;
    const ushort* pBl0 = Blo + (size_t)(n0 + r0s) * K + c0s;
    const ushort* pBl1 = Blo + (size_t)(n0 + r1s) * K + c1s;
    ushort* dst0 = lds + (size_t)wave * 512;
    ushort* dst1 = lds + (size_t)(wave + 4) * 512;

    int kz = 0, kbeg = 0, kend = K;
    if (EPI == 3) {
        kz = blockIdx.z;
        int Ks = K / gridDim.z;      // must be multiple of 32
        kbeg = kz * Ks;
        kend = kbeg + Ks;
    }

    for (int k0 = kbeg; k0 < kend; k0 += 32) {
        __syncthreads();
        gld16(pAh0 + k0, dst0);
        gld16(pAh1 + k0, dst1);
        gld16(pAl0 + k0, dst0 + 4096);
        gld16(pAl1 + k0, dst1 + 4096);
        gld16(pBh0 + k0, dst0 + 8192);
        gld16(pBh1 + k0, dst1 + 8192);
        gld16(pBl0 + k0, dst0 + 12288);
        gld16(pBl1 + k0, dst1 + 12288);
        __syncthreads();

        bf16x8 ah[4], al[4], bh[4], bl[4];
        #pragma unroll
        for (int f = 0; f < 4; f++) {
            int arow = wm64 + (f << 4) + lrow;
            int aoff = (arow << 5) + ((lkc ^ ((arow >> 1) & 3)) << 3);
            ah[f] = *(const bf16x8*)&Ash[aoff];
            al[f] = *(const bf16x8*)&Asl[aoff];
            int brow = wn64 + (f << 4) + lrow;
            int boff = (brow << 5) + ((lkc ^ ((brow >> 1) & 3)) << 3);
            bh[f] = *(const bf16x8*)&Bsh[boff];
            bl[f] = *(const bf16x8*)&Bsl[boff];
        }
        #pragma unroll
        for (int mf = 0; mf < 4; mf++)
            #pragma unroll
            for (int nf = 0; nf < 4; nf++) {
                acc[mf][nf] = __builtin_amdgcn_mfma_f32_16x16x32_bf16(
                    ah[mf], bh[nf], acc[mf][nf], 0, 0, 0);
                acc[mf][nf] = __builtin_amdgcn_mfma_f32_16x16x32_bf16(
                    ah[mf], bl[nf], acc[mf][nf], 0, 0, 0);
                acc[mf][nf] = __builtin_amdgcn_mfma_f32_16x16x32_bf16(
                    al[mf], bh[nf], acc[mf][nf], 0, 0, 0);
            }
    }

    // epilogue: C/D layout col=lane&15, row=(lane>>4)*4+reg  [m89-verified]
    const int colb = n0 + wn64 + (lane & 15);
    const int rowb = m0 + wm64 + ((lane >> 4) << 2);
    const size_t pbase = (EPI == 3) ? (size_t)kz * M * N : 0;
    #pragma unroll
    for (int nf = 0; nf < 4; nf++) {
        int col = colb + nf * 16;
        if (col >= N) continue;
        float bv = bias ? bias[col] : 0.f;
        #pragma unroll
        for (int mf = 0; mf < 4; mf++) {
            f32x4 v = acc[mf][nf];
            #pragma unroll
            for (int q = 0; q < 4; q++) {
                int row = rowb + mf * 16 + q;
                size_t idx = (size_t)row * N + col;
                float x = v[q] + bv;
                if (EPI == 1) {
                    x = 0.5f * x * (1.0f + erff(x * 0.70710678118654752f));
                    ushort hh = f2bf(x);
                    Chi[idx] = hh;
                    Clo[idx] = f2bf(x - bf2f(hh));
                } else if (EPI == 2) {
                    x += res[idx];
                    C[idx] = x;
                } else if (EPI == 3) {
                    C[pbase + idx] = x;
                } else {
                    C[idx] = x;
                }
            }
        }
    }
}

// ---------------------------------------------------------------------------
// Split-K reduce: h[i] += bias[i%N] + sum_z P[z*MN + i]   (fp32, float4)
// ---------------------------------------------------------------------------
__global__ __launch_bounds__(256) void redres_k(const float* __restrict__ P,
                                                const float* __restrict__ bias,
                                                float* __restrict__ h,
                                                int MN, int N, int KZ) {
    int i = (blockIdx.x * 256 + threadIdx.x) * 4;
    if (i >= MN) return;
    float4 s = *(const float4*)(h + i);
    float4 b = *(const float4*)(bias + (i % N));
    s.x += b.x; s.y += b.y; s.z += b.z; s.w += b.w;
    for (int z = 0; z < KZ; z++) {
        float4 pv = *(const float4*)(P + (size_t)z * MN + i);
        s.x += pv.x; s.y += pv.y; s.z += pv.z; s.w += pv.w;
    }
    *(float4*)(h + i) = s;
}

// ---------------------------------------------------------------------------
// Flash-style causal attention (fp32 compute) -> bf16 hi/lo output.
// Vectorized softmax (float4) + k-blocked PV (all-b128 LDS traffic).
// ---------------------------------------------------------------------------
__global__ __launch_bounds__(256) void attn_k(const float* __restrict__ qkv,
                                              ushort* __restrict__ oh,
                                              ushort* __restrict__ ol) {
    const int qt = blockIdx.x;
    const int hh = blockIdx.y;
    const int bb = blockIdx.z;
    const int tid = threadIdx.x;
    __shared__ __align__(16) float Qs[64][68];
    __shared__ __align__(16) float Ks[64][68];
    __shared__ __align__(16) float Vs[64][68];
    __shared__ __align__(16) float Ssm[64][68];
    __shared__ float m_s[64], l_s[64], f_s[64];

    const int q0 = qt * 64;
    const size_t base = (size_t)bb * T_SEQ * (3 * E_DIM);
    const int hoff = hh * HDIM;

    #pragma unroll
    for (int j = 0; j < 4; j++) {
        int s = tid + j * 256;
        int rr = s >> 4, c4 = (s & 15) << 2;
        *(float4*)&Qs[rr][c4] =
            *(const float4*)(qkv + base + (size_t)(q0 + rr) * (3 * E_DIM) + hoff + c4);
    }
    if (tid < 64) { m_s[tid] = -1e30f; l_s[tid] = 0.f; }

    float acc[4][4] = {};
    const int r0 = (tid >> 4) << 2, c0 = (tid & 15) << 2;
    const int rs = tid >> 2, cq = (tid & 3) << 4;

    for (int kt = 0; kt <= qt; ++kt) {
        int k0 = kt * 64;
        __syncthreads();
        #pragma unroll
        for (int j = 0; j < 4; j++) {
            int s = tid + j * 256;
            int rr = s >> 4, c4 = (s & 15) << 2;
            const float* kp = qkv + base + (size_t)(k0 + rr) * (3 * E_DIM) + hoff;
            *(float4*)&Ks[rr][c4] = *(const float4*)(kp + E_DIM + c4);
            *(float4*)&Vs[rr][c4] = *(const float4*)(kp + 2 * E_DIM + c4);
        }
        __syncthreads();

        float sacc[4][4] = {};
        #pragma unroll
        for (int d0 = 0; d0 < 64; d0 += 4) {
            float qf[4][4], kf[4][4];
            #pragma unroll
            for (int i = 0; i < 4; i++) {
                float4 v = *(const float4*)&Qs[r0 + i][d0];
                qf[i][0] = v.x; qf[i][1] = v.y; qf[i][2] = v.z; qf[i][3] = v.w;
            }
            #pragma unroll
            for (int j = 0; j < 4; j++) {
                float4 v = *(const float4*)&Ks[c0 + j][d0];
                kf[j][0] = v.x; kf[j][1] = v.y; kf[j][2] = v.z; kf[j][3] = v.w;
            }
            #pragma unroll
            for (int i = 0; i < 4; i++)
                #pragma unroll
                for (int j = 0; j < 4; j++)
                    #pragma unroll
                    for (int d = 0; d < 4; d++)
                        sacc[i][j] = fmaf(qf[i][d], kf[j][d], sacc[i][j]);
        }
        bool diag = (kt == qt);
        #pragma unroll
        for (int i = 0; i < 4; i++) {
            float4 w;
            float vv[4];
            #pragma unroll
            for (int j = 0; j < 4; j++) {
                float v = sacc[i][j] * 0.125f;
                if (diag && (c0 + j) > (r0 + i)) v = -1e9f;
                vv[j] = v;
            }
            w.x = vv[0]; w.y = vv[1]; w.z = vv[2]; w.w = vv[3];
            *(float4*)&Ssm[r0 + i][c0] = w;
        }
        __syncthreads();

        // online softmax: thread handles row rs, 16 cols at cq (4x float4)
        float4 sv[4];
        #pragma unroll
        for (int c4 = 0; c4 < 4; c4++)
            sv[c4] = *(const float4*)&Ssm[rs][cq + c4 * 4];
        float mx = -1e30f;
        #pragma unroll
        for (int c4 = 0; c4 < 4; c4++)
            mx = fmaxf(fmaxf(fmaxf(mx, sv[c4].x), fmaxf(sv[c4].y, sv[c4].z)),
                       sv[c4].w);
        mx = fmaxf(mx, __shfl_xor(mx, 1));
        mx = fmaxf(mx, __shfl_xor(mx, 2));
        float m_old = m_s[rs];
        float m_new = fmaxf(m_old, mx);
        float ps = 0.f;
        #pragma unroll
        for (int c4 = 0; c4 < 4; c4++) {
            sv[c4].x = __expf(sv[c4].x - m_new);
            sv[c4].y = __expf(sv[c4].y - m_new);
            sv[c4].z = __expf(sv[c4].z - m_new);
            sv[c4].w = __expf(sv[c4].w - m_new);
            ps += sv[c4].x + sv[c4].y + sv[c4].z + sv[c4].w;
            *(float4*)&Ssm[rs][cq + c4 * 4] = sv[c4];
        }
        ps += __shfl_xor(ps, 1);
        ps += __shfl_xor(ps, 2);
        if ((tid & 3) == 0) {
            float f = __expf(m_old - m_new);
            l_s[rs] = l_s[rs] * f + ps;
            m_s[rs] = m_new;
            f_s[rs] = f;
        }
        __syncthreads();

        // rescale + PV (k-blocked, float4 LDS reads only; same fp32 k-order)
        #pragma unroll
        for (int i = 0; i < 4; i++) {
            float f = f_s[r0 + i];
            #pragma unroll
            for (int j = 0; j < 4; j++) acc[i][j] *= f;
        }
        #pragma unroll 4
        for (int k4 = 0; k4 < 64; k4 += 4) {
            float4 pr[4], vr[4];
            #pragma unroll
            for (int i = 0; i < 4; i++) pr[i] = *(const float4*)&Ssm[r0 + i][k4];
            #pragma unroll
            for (int d = 0; d < 4; d++) vr[d] = *(const float4*)&Vs[k4 + d][c0];
            #pragma unroll
            for (int i = 0; i < 4; i++) {
                float pf[4] = {pr[i].x, pr[i].y, pr[i].z, pr[i].w};
                #pragma unroll
                for (int d = 0; d < 4; d++) {
                    acc[i][0] = fmaf(pf[d], vr[d].x, acc[i][0]);
                    acc[i][1] = fmaf(pf[d], vr[d].y, acc[i][1]);
                    acc[i][2] = fmaf(pf[d], vr[d].z, acc[i][2]);
                    acc[i][3] = fmaf(pf[d], vr[d].w, acc[i][3]);
                }
            }
        }
    }

    #pragma unroll
    for (int i = 0; i < 4; i++) {
        float inv = 1.0f / l_s[r0 + i];
        size_t idx = (size_t)(bb * T_SEQ + q0 + r0 + i) * E_DIM + hoff + c0;
        ushort hv[4], lv[4];
        #pragma unroll
        for (int j = 0; j < 4; j++) {
            float v = acc[i][j] * inv;
            hv[j] = f2bf(v);
            lv[j] = f2bf(v - bf2f(hv[j]));
        }
        uint2 ph, pl;
        ph.x = (uint)hv[0] | ((uint)hv[1] << 16); ph.y = (uint)hv[2] | ((uint)hv[3] << 16);
        pl.x = (uint)lv[0] | ((uint)lv[1] << 16); pl.y = (uint)lv[2] | ((uint)lv[3] << 16);
        *(uint2*)(oh + idx) = ph;
        *(uint2*)(ol + idx) = pl;
    }
}

// ---------------------------------------------------------------------------
// Launch
// ---------------------------------------------------------------------------
static inline char* al256(char* p) {
    return (char*)(((uintptr_t)p + 255) & ~(uintptr_t)255);
}

extern "C" void kernel_launch(void* const* d_in, const int* in_sizes, int n_in,
                              void* d_out, int out_size, void* d_ws, size_t ws_size,
                              hipStream_t stream) {
    const int* x        = (const int*)d_in[0];
    const float* tok    = (const float*)d_in[1];
    const float* pos    = (const float*)d_in[2];
    const float* ln1_w  = (const float*)d_in[3];
    const float* ln1_b  = (const float*)d_in[4];
    const float* qkv_w  = (const float*)d_in[5];
    const float* qkv_b  = (const float*)d_in[6];
    const float* out_w  = (const float*)d_in[7];
    const float* out_b  = (const float*)d_in[8];
    const float* ln2_w  = (const float*)d_in[9];
    const float* ln2_b  = (const float*)d_in[10];
    const float* mlp_w1 = (const float*)d_in[11];
    const float* mlp_b1 = (const float*)d_in[12];
    const float* mlp_w2 = (const float*)d_in[13];
    const float* mlp_b2 = (const float*)d_in[14];
    const float* lnf_w  = (const float*)d_in[15];
    const float* lnf_b  = (const float*)d_in[16];
    const float* head_w = (const float*)d_in[17];
    float* out = (float*)d_out;

    // ---- activation sizes (bytes)
    const size_t Zh   = (size_t)BT * E_DIM * 4;
    const size_t Zqkv = (size_t)BT * 3 * E_DIM * 4;
    const size_t Zbf  = (size_t)BT * E_DIM * 2;          // one bf16 activation
    const size_t Zm1  = (size_t)BT * 4 * E_DIM * 2;
    const size_t ZP   = (size_t)8 * BT * E_DIM * 4;      // split-K partials (KZ<=8)
    // weight (transposed, per buffer = hi or lo) sizes
    const size_t ZqT  = (size_t)3 * E_DIM * E_DIM * 2;
    const size_t ZoT  = (size_t)E_DIM * E_DIM * 2;
    const size_t Zw1T = (size_t)4 * E_DIM * E_DIM * 2;
    const size_t Zw2T = (size_t)4 * E_DIM * E_DIM * 2;
    const size_t ZhT  = (size_t)VPAD * E_DIM * 2;

    char* base = (char*)d_ws;
    char* p = base;
    auto take = [&](size_t bytes) { char* r = p; p = al256(p + bytes); return r; };

    // ---- try BIG layout: all-layer weights + split-K partials
    float*  h    = (float*)take(Zh);
    float*  qkvb = (float*)take(Zqkv);
    ushort* hnh  = (ushort*)take(Zbf);
    ushort* hnl  = (ushort*)take(Zbf);
    ushort* obh  = (ushort*)take(Zbf);
    ushort* obl  = (ushort*)take(Zbf);
    ushort* m1h  = (ushort*)take(Zm1);
    ushort* m1l  = (ushort*)take(Zm1);
    float*  Pbuf = (float*)take(ZP);
    ushort* qTh  = (ushort*)take(ZqT * NLAYER);
    ushort* qTl  = (ushort*)take(ZqT * NLAYER);
    ushort* oTh  = (ushort*)take(ZoT * NLAYER);
    ushort* oTl  = (ushort*)take(ZoT * NLAYER);
    ushort* w1h  = (ushort*)take(Zw1T * NLAYER);
    ushort* w1l  = (ushort*)take(Zw1T * NLAYER);
    ushort* w2h  = (ushort*)take(Zw2T * NLAYER);
    ushort* w2l  = (ushort*)take(Zw2T * NLAYER);
    ushort* hTh  = (ushort*)take(ZhT);
    ushort* hTl  = (ushort*)take(ZhT);
    bool big = (size_t)(p - base) <= ws_size;

    if (!big) {
        // fallback: round-3 layout (known-good at ~246 MB), per-layer tconv,
        // no split-K
        p = base;
        h    = (float*)take(Zh);
        qkvb = (float*)take(Zqkv);
        hnh  = (ushort*)take(Zbf);
        hnl  = (ushort*)take(Zbf);
        obh  = (ushort*)take(Zbf);
        obl  = (ushort*)take(Zbf);
        m1h  = (ushort*)take(Zm1);
        m1l  = (ushort*)take(Zm1);
        qTh  = (ushort*)take(ZqT);
        qTl  = (ushort*)take(ZqT);
        oTh  = (ushort*)take(ZoT);
        oTl  = (ushort*)take(ZoT);
        w1h  = (ushort*)take(Zw1T);
        w1l  = (ushort*)take(Zw1T);
        w2h  = (ushort*)take(Zw2T);
        w2l  = (ushort*)take(Zw2T);
        hTh  = (ushort*)take(ZhT);
        hTl  = (ushort*)take(ZhT);
        Pbuf = nullptr;
    }

    if (big) {
        // batched weight transposes (once, up-front; grid.z = layer)
        tconv_k<<<dim3(E_DIM / 32, 3 * E_DIM / 32, NLAYER), 256, 0, stream>>>(
            qkv_w, qTh, qTl, E_DIM, 3 * E_DIM, 3 * E_DIM);
        tconv_k<<<dim3(E_DIM / 32, E_DIM / 32, NLAYER), 256, 0, stream>>>(
            out_w, oTh, oTl, E_DIM, E_DIM, E_DIM);
        tconv_k<<<dim3(E_DIM / 32, 4 * E_DIM / 32, NLAYER), 256, 0, stream>>>(
            mlp_w1, w1h, w1l, E_DIM, 4 * E_DIM, 4 * E_DIM);
        tconv_k<<<dim3(4 * E_DIM / 32, E_DIM / 32, NLAYER), 256, 0, stream>>>(
            mlp_w2, w2h, w2l, 4 * E_DIM, E_DIM, E_DIM);
        tconv_k<<<dim3(E_DIM / 32, VPAD / 32, 1), 256, 0, stream>>>(
            head_w, hTh, hTl, E_DIM, VOCAB, VPAD);
    }

    embed_k<<<BT, 192, 0, stream>>>(x, tok, pos, h);

    for (int l = 0; l < NLAYER; ++l) {
        const ushort *qThl, *qTll, *oThl, *oTll, *w1hl, *w1ll, *w2hl, *w2ll;
        if (big) {
            qThl = qTh + (size_t)l * (ZqT / 2);  qTll = qTl + (size_t)l * (ZqT / 2);
            oThl = oTh + (size_t)l * (ZoT / 2);  oTll = oTl + (size_t)l * (ZoT / 2);
            w1hl = w1h + (size_t)l * (Zw1T / 2); w1ll = w1l + (size_t)l * (Zw1T / 2);
            w2hl = w2h + (size_t)l * (Zw2T / 2); w2ll = w2l + (size_t)l * (Zw2T / 2);
        } else {
            tconv_k<<<dim3(E_DIM / 32, 3 * E_DIM / 32, 1), 256, 0, stream>>>(
                qkv_w + (size_t)l * E_DIM * 3 * E_DIM, qTh, qTl,
                E_DIM, 3 * E_DIM, 3 * E_DIM);
            tconv_k<<<dim3(E_DIM / 32, E_DIM / 32, 1), 256, 0, stream>>>(
                out_w + (size_t)l * E_DIM * E_DIM, oTh, oTl, E_DIM, E_DIM, E_DIM);
            tconv_k<<<dim3(E_DIM / 32, 4 * E_DIM / 32, 1), 256, 0, stream>>>(
                mlp_w1 + (size_t)l * E_DIM * 4 * E_DIM, w1h, w1l,
                E_DIM, 4 * E_DIM, 4 * E_DIM);
            tconv_k<<<dim3(4 * E_DIM / 32, E_DIM / 32, 1), 256, 0, stream>>>(
                mlp_w2 + (size_t)l * 4 * E_DIM * E_DIM, w2h, w2l,
                4 * E_DIM, E_DIM, E_DIM);
            qThl = qTh; qTll = qTl; oThl = oTh; oTll = oTl;
            w1hl = w1h; w1ll = w1l; w2hl = w2h; w2ll = w2l;
        }

        ln_k<<<BT, 256, 0, stream>>>(h, ln1_w + l * E_DIM, ln1_b + l * E_DIM,
                                     hnh, hnl);
        gemmf_k<0><<<dim3(3 * E_DIM / 128, BT / 128), 256, 0, stream>>>(
            hnh, hnl, qThl, qTll, qkv_b + (size_t)l * 3 * E_DIM, nullptr,
            qkvb, nullptr, nullptr, BT, 3 * E_DIM, E_DIM);
        attn_k<<<dim3(T_SEQ / 64, NHEAD, 2), 256, 0, stream>>>(qkvb, obh, obl);

        if (big) {  // out-proj split-K x2 + fused reduce(bias+residual)
            gemmf_k<3><<<dim3(E_DIM / 128, BT / 128, 2), 256, 0, stream>>>(
                obh, obl, oThl, oTll, nullptr, nullptr,
                Pbuf, nullptr, nullptr, BT, E_DIM, E_DIM);
            redres_k<<<(BT * E_DIM / 4 + 255) / 256, 256, 0, stream>>>(
                Pbuf, out_b + (size_t)l * E_DIM, h, BT * E_DIM, E_DIM, 2);
        } else {
            gemmf_k<2><<<dim3(E_DIM / 128, BT / 128), 256, 0, stream>>>(
                obh, obl, oThl, oTll, out_b + (size_t)l * E_DIM, h,
                h, nullptr, nullptr, BT, E_DIM, E_DIM);
        }

        ln_k<<<BT, 256, 0, stream>>>(h, ln2_w + l * E_DIM, ln2_b + l * E_DIM,
                                     hnh, hnl);
        gemmf_k<1><<<dim3(4 * E_DIM / 128, BT / 128), 256, 0, stream>>>(
            hnh, hnl, w1hl, w1ll, mlp_b1 + (size_t)l * 4 * E_DIM, nullptr,
            nullptr, m1h, m1l, BT, 4 * E_DIM, E_DIM);

        if (big) {  // MLP2 split-K x8 + fused reduce
            gemmf_k<3><<<dim3(E_DIM / 128, BT / 128, 8), 256, 0, stream>>>(
                m1h, m1l, w2hl, w2ll, nullptr, nullptr,
                Pbuf, nullptr, nullptr, BT, E_DIM, 4 * E_DIM);
            redres_k<<<(BT * E_DIM / 4 + 255) / 256, 256, 0, stream>>>(
                Pbuf, mlp_b2 + (size_t)l * E_DIM, h, BT * E_DIM, E_DIM, 8);
        } else {
            gemmf_k<2><<<dim3(E_DIM / 128, BT / 128), 256, 0, stream>>>(
                m1h, m1l, w2hl, w2ll, mlp_b2 + (size_t)l * E_DIM, h,
                h, nullptr, nullptr, BT, E_DIM, 4 * E_DIM);
        }
    }

    if (!big) {
        tconv_k<<<dim3(E_DIM / 32, VPAD / 32, 1), 256, 0, stream>>>(
            head_w, hTh, hTl, E_DIM, VOCAB, VPAD);
    }
    ln_k<<<BT, 256, 0, stream>>>(h, lnf_w, lnf_b, hnh, hnl);
    gemmf_k<0><<<dim3(VPAD / 128, BT / 128), 256, 0, stream>>>(
        hnh, hnl, hTh, hTl, nullptr, nullptr,
        out, nullptr, nullptr, BT, VOCAB, E_DIM);
}